// Round 1
// baseline (481.011 us; speedup 1.0000x reference)
//
#include <hip/hip_runtime.h>

// Problem constants (n=8, c=64, h=w=256, points=8192)
#define NB    8
#define NC    64
#define HDIM  256
#define HW    65536        // 256*256
#define NPTS  8192
#define TOTPTS (NB*NPTS)   // 65536
#define N1    33554432     // 8*64*256*256 (x_out elements)

__device__ __forceinline__ int reflect_idx(int t) {
    t = t < 0 ? -t : t;
    return t > 255 ? 510 - t : t;
}

// ---------------------------------------------------------------------------
// NCHW -> NHWC transpose of x2 (per batch: 64 x 65536 -> 65536 x 64)
// Block = 256 threads, tile = 64(hw) x 64(c), LDS padded to kill bank conflicts
// ---------------------------------------------------------------------------
__global__ __launch_bounds__(256) void transpose_kernel(
    const float* __restrict__ x2, float* __restrict__ x2t)
{
    __shared__ float tile[64][65];
    int nb  = blockIdx.x;          // 0..8191  (8 n * 1024 tiles)
    int n   = nb >> 10;
    int hw0 = (nb & 1023) << 6;    // tile base in hw
    int t    = threadIdx.x;
    int lane = t & 63;
    int grp  = t >> 6;             // wave id 0..3
    const float* src = x2 + ((size_t)n << 22);   // n*64*65536
#pragma unroll
    for (int i = 0; i < 16; ++i) {
        int c = (grp << 4) + i;    // each wave covers 16 channels
        tile[lane][c] = src[((size_t)c << 16) + (size_t)(hw0 + lane)];
    }
    __syncthreads();
    float* dst = x2t + (((size_t)n << 16) + (size_t)hw0) * NC;
#pragma unroll
    for (int i = 0; i < 16; ++i) {
        int hw = (grp << 4) + i;
        dst[((size_t)hw << 6) + lane] = tile[hw][lane];
    }
}

// ---------------------------------------------------------------------------
// Attention kernel: one wave (64 lanes = 64 channels) per sampled point.
// NHWC=true  -> x2b is the NHWC transposed buffer (coalesced 256B loads / k)
// COMPACT=true -> write final value (x1 + alpha*fusion) into fusion_buf and
//                 record winner in map; else scatter directly into out.
// ---------------------------------------------------------------------------
template<bool NHWC, bool COMPACT>
__global__ __launch_bounds__(256) void attn_kernel(
    const float* __restrict__ x1, const float* __restrict__ x2b,
    const int* __restrict__ sfl, const float* __restrict__ alpha_p,
    float* __restrict__ fusion_buf, int* __restrict__ map,
    float* __restrict__ out)
{
    int p    = (blockIdx.x << 2) + (threadIdx.x >> 6);  // point id, 0..65535
    int lane = threadIdx.x & 63;                         // channel
    int n    = p >> 13;                                  // 8192 points per n
    int ph   = sfl[2 * p];
    int pw   = sfl[2 * p + 1];
    float alpha = alpha_p[0];

    size_t x1idx = (((size_t)(n * NC + lane)) << 16) + (size_t)((ph << 8) + pw);
    float xp = x1[x1idx];

    float xa[25];
#pragma unroll
    for (int k = 0; k < 25; ++k) {
        int rh = reflect_idx(ph + k / 5 - 2);
        int rw = reflect_idx(pw + k % 5 - 2);
        size_t idx;
        if (NHWC)
            idx = ((((size_t)n << 16) + (size_t)((rh << 8) + rw)) << 6) + lane;
        else
            idx = (((size_t)(n * NC + lane)) << 16) + (size_t)((rh << 8) + rw);
        xa[k] = x2b[idx];
    }

    // energy[k] = sum_c xp*xa[k] : 6-step xor butterfly -> all lanes hold sum
    float e[25];
#pragma unroll
    for (int k = 0; k < 25; ++k) {
        float v = xp * xa[k];
        v += __shfl_xor(v, 32);
        v += __shfl_xor(v, 16);
        v += __shfl_xor(v, 8);
        v += __shfl_xor(v, 4);
        v += __shfl_xor(v, 2);
        v += __shfl_xor(v, 1);
        e[k] = v;
    }

    // softmax over 25 (redundantly in every lane - pure VALU)
    float m = e[0];
#pragma unroll
    for (int k = 1; k < 25; ++k) m = fmaxf(m, e[k]);
    float s = 0.f;
#pragma unroll
    for (int k = 0; k < 25; ++k) { e[k] = __expf(e[k] - m); s += e[k]; }
    float inv = __frcp_rn(s);

    float f = 0.f;
#pragma unroll
    for (int k = 0; k < 25; ++k) f += e[k] * xa[k];
    f *= inv;

    float val = xp + alpha * f;

    if (COMPACT) {
        fusion_buf[((size_t)p << 6) + lane] = val;
        if (lane == 0) map[(n << 16) + (ph << 8) + pw] = p;  // benign race: dups identical
    } else {
        out[x1idx] = val;
    }
}

// ---------------------------------------------------------------------------
// Merge kernel: out = x1*(1+alpha), overridden at sampled positions from the
// compact fusion buffer via the winner map. float4 over [n][c][hw].
// ---------------------------------------------------------------------------
template<bool HAVE_MAP>
__global__ __launch_bounds__(256) void merge_kernel(
    const float* __restrict__ x1, const float* __restrict__ alpha_p,
    const int* __restrict__ map, const float* __restrict__ fusion_buf,
    float* __restrict__ out)
{
    size_t g = (size_t)blockIdx.x * 256 + threadIdx.x;   // float4 index
    float alpha = alpha_p[0];
    float4 x = ((const float4*)x1)[g];
    float sc = 1.0f + alpha;
    float4 o;
    o.x = x.x * sc; o.y = x.y * sc; o.z = x.z * sc; o.w = x.w * sc;
    if (HAVE_MAP) {
        int hw4 = (int)(g & 16383);
        int c   = (int)((g >> 14) & 63);
        int n   = (int)(g >> 20);
        int4 w4 = ((const int4*)map)[((size_t)n << 14) + hw4];
        if (w4.x >= 0) o.x = fusion_buf[((size_t)w4.x << 6) + c];
        if (w4.y >= 0) o.y = fusion_buf[((size_t)w4.y << 6) + c];
        if (w4.z >= 0) o.z = fusion_buf[((size_t)w4.z << 6) + c];
        if (w4.w >= 0) o.w = fusion_buf[((size_t)w4.w << 6) + c];
    }
    ((float4*)out)[g] = o;
}

// SFL echoed as float32 into the output tail
__global__ __launch_bounds__(256) void tail_kernel(
    const int* __restrict__ sfl, float* __restrict__ outtail)
{
    int i = blockIdx.x * 256 + threadIdx.x;   // 0..131071
    outtail[i] = (float)sfl[i];
}

extern "C" void kernel_launch(void* const* d_in, const int* in_sizes, int n_in,
                              void* d_out, int out_size, void* d_ws, size_t ws_size,
                              hipStream_t stream)
{
    const float* x1    = (const float*)d_in[0];
    const float* x2    = (const float*)d_in[1];
    const int*   sfl   = (const int*)d_in[2];
    const float* alpha = (const float*)d_in[3];
    float* out = (float*)d_out;

    const size_t X2T_BYTES = (size_t)NB * HW * NC * 4;   // 134,217,728
    const size_t FUS_BYTES = (size_t)TOTPTS * NC * 4;    //  16,777,216
    const size_t MAP_BYTES = (size_t)NB * HW * 4;        //   2,097,152

    if (ws_size >= X2T_BYTES + FUS_BYTES + MAP_BYTES) {
        // Tier A: transpose + compact fusion + gather-merge
        float* x2t = (float*)d_ws;
        float* fus = (float*)((char*)d_ws + X2T_BYTES);
        int*   map = (int*)((char*)d_ws + X2T_BYTES + FUS_BYTES);
        hipMemsetAsync(map, 0xFF, MAP_BYTES, stream);
        transpose_kernel<<<8192, 256, 0, stream>>>(x2, x2t);
        attn_kernel<true, true><<<TOTPTS / 4, 256, 0, stream>>>(
            x1, x2t, sfl, alpha, fus, map, nullptr);
        merge_kernel<true><<<N1 / 4 / 256, 256, 0, stream>>>(x1, alpha, map, fus, out);
        tail_kernel<<<(TOTPTS * 2) / 256, 256, 0, stream>>>(sfl, out + N1);
    } else if (ws_size >= FUS_BYTES + MAP_BYTES) {
        // Tier B: no transpose (slow NCHW gather) + compact fusion + merge
        float* fus = (float*)d_ws;
        int*   map = (int*)((char*)d_ws + FUS_BYTES);
        hipMemsetAsync(map, 0xFF, MAP_BYTES, stream);
        attn_kernel<false, true><<<TOTPTS / 4, 256, 0, stream>>>(
            x1, x2, sfl, alpha, fus, map, nullptr);
        merge_kernel<true><<<N1 / 4 / 256, 256, 0, stream>>>(x1, alpha, map, fus, out);
        tail_kernel<<<(TOTPTS * 2) / 256, 256, 0, stream>>>(sfl, out + N1);
    } else {
        // Tier C: no workspace — base pass then direct scatter (dups benign)
        merge_kernel<false><<<N1 / 4 / 256, 256, 0, stream>>>(
            x1, alpha, nullptr, nullptr, out);
        attn_kernel<false, false><<<TOTPTS / 4, 256, 0, stream>>>(
            x1, x2, sfl, alpha, nullptr, nullptr, out);
        tail_kernel<<<(TOTPTS * 2) / 256, 256, 0, stream>>>(sfl, out + N1);
    }
}